// Round 1
// baseline (2196.674 us; speedup 1.0000x reference)
//
#include <hip/hip_runtime.h>
#include <math.h>

#define S_ 512
#define B_ 64
#define C_ 1024
#define T_ 128
#define V_ 10
#define LN_EPS 1e-5f

// ---------- Phase 1a: per (t,b): softmax(values@Wd.T+bd), sigmoid(values@Wr[1]+br[1])
// one wave per (t,b); stores float4 {d0,d1,d2,rw1} at dtr[(t*64+b)*4]
__global__ __launch_bounds__(256) void k_dirs(const float* __restrict__ values,
                                              const float* __restrict__ Wd,
                                              const float* __restrict__ bd,
                                              const float* __restrict__ Wr,
                                              const float* __restrict__ br,
                                              float* __restrict__ dtr) {
    int wid  = (blockIdx.x << 2) + (threadIdx.x >> 6);   // 0..32767 = t*64+b
    int lane = threadIdx.x & 63;
    const float4* v4  = (const float4*)(values + (size_t)wid * C_);
    const float4* wd4 = (const float4*)Wd;
    const float4* wr4 = (const float4*)Wr;
    float a0 = 0.f, a1 = 0.f, a2 = 0.f, a3 = 0.f;
#pragma unroll
    for (int k = 0; k < 4; k++) {
        int i = (k << 6) + lane;           // float4 index within 256
        float4 v  = v4[i];
        float4 w0 = wd4[i];
        float4 w1 = wd4[256 + i];
        float4 w2 = wd4[512 + i];
        float4 w3 = wr4[256 + i];          // Wr row 1
        a0 = fmaf(v.x, w0.x, fmaf(v.y, w0.y, fmaf(v.z, w0.z, fmaf(v.w, w0.w, a0))));
        a1 = fmaf(v.x, w1.x, fmaf(v.y, w1.y, fmaf(v.z, w1.z, fmaf(v.w, w1.w, a1))));
        a2 = fmaf(v.x, w2.x, fmaf(v.y, w2.y, fmaf(v.z, w2.z, fmaf(v.w, w2.w, a2))));
        a3 = fmaf(v.x, w3.x, fmaf(v.y, w3.y, fmaf(v.z, w3.z, fmaf(v.w, w3.w, a3))));
    }
#pragma unroll
    for (int m = 1; m < 64; m <<= 1) {
        a0 += __shfl_xor(a0, m, 64);
        a1 += __shfl_xor(a1, m, 64);
        a2 += __shfl_xor(a2, m, 64);
        a3 += __shfl_xor(a3, m, 64);
    }
    if (lane == 0) {
        float l0 = a0 + bd[0], l1 = a1 + bd[1], l2 = a2 + bd[2];
        float mx = fmaxf(fmaxf(l0, l1), l2);
        float e0 = __expf(l0 - mx), e1 = __expf(l1 - mx), e2 = __expf(l2 - mx);
        float inv = 1.f / (e0 + e1 + e2);
        float r = 1.f / (1.f + __expf(-(a3 + br[1])));
        ((float4*)dtr)[wid] = make_float4(e0 * inv, e1 * inv, e2 * inv, r);
    }
}

// ---------- Phase 1b: evolve pos per batch; store pos_t (pre-update) for all t.
// one wave per b; pos[l] split: lane holds l=lane (p0) and l=lane+64 (p1).
__global__ __launch_bounds__(64) void k_pos(const float* __restrict__ dtr,
                                            float* __restrict__ pos_all) {
    int b = blockIdx.x;
    int lane = threadIdx.x;
    const float4* dtr4 = (const float4*)dtr;
    float4 dreg[8];
#pragma unroll
    for (int k = 0; k < 8; k++)
        dreg[k] = dtr4[(((size_t)(k << 6) + lane) << 6) + b];   // t = k*64+lane
    float p0 = (lane == 0) ? 1.f : 0.f;
    float p1 = 0.f;
    float* outp = pos_all + ((size_t)b << 7) + lane;
    int up = (lane + 1) & 63, dw = (lane + 63) & 63;
#pragma unroll
    for (int k = 0; k < 8; k++) {
#pragma unroll 4
        for (int tt = 0; tt < 64; tt++) {
            int t = (k << 6) + tt;
            float d0 = __shfl(dreg[k].x, tt, 64);
            float d1 = __shfl(dreg[k].y, tt, 64);
            float d2 = __shfl(dreg[k].z, tt, 64);
            outp[(size_t)t * (B_ * T_)]      = p0;   // pos_t before update
            outp[(size_t)t * (B_ * T_) + 64] = p1;
            float s0n = __shfl(p0, up, 64), s1n = __shfl(p1, up, 64);
            float s0p = __shfl(p0, dw, 64), s1p = __shfl(p1, dw, 64);
            float up0 = (lane == 63) ? s1n : s0n;   // pos[(l+1)%128], l=lane
            float dn0 = (lane == 0)  ? s1p : s0p;   // pos[(l-1)%128]
            float up1 = (lane == 63) ? s0n : s1n;   // l=lane+64
            float dn1 = (lane == 0)  ? s0p : s1p;
            p0 = fmaf(up0, d0, fmaf(p0, d1, dn0 * d2));
            p1 = fmaf(up1, d0, fmaf(p1, d1, dn1 * d2));
        }
    }
}

// ---------- Phase 2: the scan. thread = (b,c); tape column in 128 VGPRs.
__global__ __launch_bounds__(256, 1) void k_scan(const float* __restrict__ values,
                                                 const float* __restrict__ dtr,
                                                 const float* __restrict__ pos_all,
                                                 float* __restrict__ tape_out) {
    int b = blockIdx.x >> 2;
    int c = ((blockIdx.x & 3) << 8) + threadIdx.x;
    float tape[T_];
#pragma unroll
    for (int l = 0; l < T_; l++) tape[l] = 0.f;
    const float* vp = values + (size_t)b * C_ + c;
    float vnext = *vp;
    for (int t = 0; t < S_; t++) {
        float v = vnext;
        int tn = (t + 1 < S_) ? (t + 1) : (S_ - 1);
        vnext = vp[(size_t)tn * (B_ * C_)];
        float rw = dtr[(((size_t)t << 6) + b) * 4 + 3];          // uniform -> s_load
        const float4* p4 = (const float4*)(pos_all + ((size_t)t * B_ + b) * T_);
        float ov0 = 0.f, ov1 = 0.f, ov2 = 0.f, ov3 = 0.f;
#pragma unroll
        for (int j = 0; j < 32; j++) {
            float4 q = p4[j];                                    // uniform -> s_load
            ov0 = fmaf(tape[4 * j],     q.x, ov0);
            ov1 = fmaf(tape[4 * j + 1], q.y, ov1);
            ov2 = fmaf(tape[4 * j + 2], q.z, ov2);
            ov3 = fmaf(tape[4 * j + 3], q.w, ov3);
        }
        float delta = (v - ((ov0 + ov1) + (ov2 + ov3))) * rw;
#pragma unroll
        for (int j = 0; j < 32; j++) {
            float4 q = p4[j];
            tape[4 * j]     = fmaf(q.x, delta, tape[4 * j]);
            tape[4 * j + 1] = fmaf(q.y, delta, tape[4 * j + 1]);
            tape[4 * j + 2] = fmaf(q.z, delta, tape[4 * j + 2]);
            tape[4 * j + 3] = fmaf(q.w, delta, tape[4 * j + 3]);
        }
    }
    float* tp = tape_out + (size_t)b * C_ + c;                   // layout [l][b][c]
#pragma unroll
    for (int l = 0; l < T_; l++) tp[(size_t)l * (B_ * C_)] = tape[l];
}

// ---------- Phase 3: LayerNorm over C + projection to V=10. one wave per (l,b).
__global__ __launch_bounds__(256) void k_out(const float* __restrict__ tape,
                                             const float* __restrict__ ln_g,
                                             const float* __restrict__ ln_b,
                                             const float* __restrict__ Wo,
                                             const float* __restrict__ bo,
                                             float* __restrict__ out) {
    int wid  = (blockIdx.x << 2) + (threadIdx.x >> 6);   // 0..8191 = l*64+b
    int lane = threadIdx.x & 63;
    const float* tr = tape + (size_t)wid * C_;
    float x[16];
    float s = 0.f, s2 = 0.f;
#pragma unroll
    for (int k = 0; k < 16; k++) {
        x[k] = tr[(k << 6) + lane];
        s += x[k];
        s2 = fmaf(x[k], x[k], s2);
    }
#pragma unroll
    for (int m = 1; m < 64; m <<= 1) {
        s  += __shfl_xor(s,  m, 64);
        s2 += __shfl_xor(s2, m, 64);
    }
    float mu = s * (1.f / C_);
    float var = s2 * (1.f / C_) - mu * mu;
    float rstd = rsqrtf(var + LN_EPS);
    float acc[V_];
#pragma unroll
    for (int v = 0; v < V_; v++) acc[v] = 0.f;
#pragma unroll
    for (int k = 0; k < 16; k++) {
        int cc = (k << 6) + lane;
        float h = fmaf((x[k] - mu) * rstd, ln_g[cc], ln_b[cc]);
#pragma unroll
        for (int v = 0; v < V_; v++) acc[v] = fmaf(h, Wo[v * C_ + cc], acc[v]);
    }
#pragma unroll
    for (int v = 0; v < V_; v++) {
#pragma unroll
        for (int m = 1; m < 64; m <<= 1) acc[v] += __shfl_xor(acc[v], m, 64);
    }
    if (lane == 0) {
#pragma unroll
        for (int v = 0; v < V_; v++) out[(size_t)wid * V_ + v] = acc[v] + bo[v];
    }
}

extern "C" void kernel_launch(void* const* d_in, const int* in_sizes, int n_in,
                              void* d_out, int out_size, void* d_ws, size_t ws_size,
                              hipStream_t stream) {
    const float* values = (const float*)d_in[0];
    const float* Wd     = (const float*)d_in[1];
    const float* bd     = (const float*)d_in[2];
    const float* Wr     = (const float*)d_in[3];
    const float* br     = (const float*)d_in[4];
    const float* ln_g   = (const float*)d_in[5];
    const float* ln_b   = (const float*)d_in[6];
    const float* Wo     = (const float*)d_in[7];
    const float* bo     = (const float*)d_in[8];
    float* out = (float*)d_out;

    // workspace layout (floats): dtr [512*64*4] | pos_all [512*64*128] | tape [128*64*1024]
    float* dtr     = (float*)d_ws;
    float* pos_all = dtr + (size_t)S_ * B_ * 4;
    float* tape    = pos_all + (size_t)S_ * B_ * T_;

    k_dirs<<<dim3((S_ * B_) / 4), dim3(256), 0, stream>>>(values, Wd, bd, Wr, br, dtr);
    k_pos <<<dim3(B_),            dim3(64),  0, stream>>>(dtr, pos_all);
    k_scan<<<dim3(B_ * 4),        dim3(256), 0, stream>>>(values, dtr, pos_all, tape);
    k_out <<<dim3((T_ * B_) / 4), dim3(256), 0, stream>>>(tape, ln_g, ln_b, Wo, bo, out);
}

// Round 2
// 769.011 us; speedup vs baseline: 2.8565x; 2.8565x over previous
//
#include <hip/hip_runtime.h>
#include <math.h>

#define S_ 512
#define B_ 64
#define C_ 1024
#define T_ 128
#define V_ 10
#define LN_EPS 1e-5f

// ---------- Phase 1a: per (t,b): softmax(values@Wd.T+bd), sigmoid(values@Wr[1]+br[1])
// one wave per (t,b); stores float4 {d0,d1,d2,rw1} at dtr[(t*64+b)*4]
__global__ __launch_bounds__(256) void k_dirs(const float* __restrict__ values,
                                              const float* __restrict__ Wd,
                                              const float* __restrict__ bd,
                                              const float* __restrict__ Wr,
                                              const float* __restrict__ br,
                                              float* __restrict__ dtr) {
    int wid  = (blockIdx.x << 2) + (threadIdx.x >> 6);   // 0..32767 = t*64+b
    int lane = threadIdx.x & 63;
    const float4* v4  = (const float4*)(values + (size_t)wid * C_);
    const float4* wd4 = (const float4*)Wd;
    const float4* wr4 = (const float4*)Wr;
    float a0 = 0.f, a1 = 0.f, a2 = 0.f, a3 = 0.f;
#pragma unroll
    for (int k = 0; k < 4; k++) {
        int i = (k << 6) + lane;           // float4 index within 256
        float4 v  = v4[i];
        float4 w0 = wd4[i];
        float4 w1 = wd4[256 + i];
        float4 w2 = wd4[512 + i];
        float4 w3 = wr4[256 + i];          // Wr row 1
        a0 = fmaf(v.x, w0.x, fmaf(v.y, w0.y, fmaf(v.z, w0.z, fmaf(v.w, w0.w, a0))));
        a1 = fmaf(v.x, w1.x, fmaf(v.y, w1.y, fmaf(v.z, w1.z, fmaf(v.w, w1.w, a1))));
        a2 = fmaf(v.x, w2.x, fmaf(v.y, w2.y, fmaf(v.z, w2.z, fmaf(v.w, w2.w, a2))));
        a3 = fmaf(v.x, w3.x, fmaf(v.y, w3.y, fmaf(v.z, w3.z, fmaf(v.w, w3.w, a3))));
    }
#pragma unroll
    for (int m = 1; m < 64; m <<= 1) {
        a0 += __shfl_xor(a0, m, 64);
        a1 += __shfl_xor(a1, m, 64);
        a2 += __shfl_xor(a2, m, 64);
        a3 += __shfl_xor(a3, m, 64);
    }
    if (lane == 0) {
        float l0 = a0 + bd[0], l1 = a1 + bd[1], l2 = a2 + bd[2];
        float mx = fmaxf(fmaxf(l0, l1), l2);
        float e0 = __expf(l0 - mx), e1 = __expf(l1 - mx), e2 = __expf(l2 - mx);
        float inv = 1.f / (e0 + e1 + e2);
        float r = 1.f / (1.f + __expf(-(a3 + br[1])));
        ((float4*)dtr)[wid] = make_float4(e0 * inv, e1 * inv, e2 * inv, r);
    }
}

// ---------- Phase 1b: evolve pos per batch; store pos_t (pre-update) for all t.
// one wave per b; pos[l] split: lane holds l=lane (p0) and l=lane+64 (p1).
__global__ __launch_bounds__(64) void k_pos(const float* __restrict__ dtr,
                                            float* __restrict__ pos_all) {
    int b = blockIdx.x;
    int lane = threadIdx.x;
    const float4* dtr4 = (const float4*)dtr;
    float4 dreg[8];
#pragma unroll
    for (int k = 0; k < 8; k++)
        dreg[k] = dtr4[(((size_t)(k << 6) + lane) << 6) + b];   // t = k*64+lane
    float p0 = (lane == 0) ? 1.f : 0.f;
    float p1 = 0.f;
    float* outp = pos_all + ((size_t)b << 7) + lane;
    int up = (lane + 1) & 63, dw = (lane + 63) & 63;
#pragma unroll
    for (int k = 0; k < 8; k++) {
#pragma unroll 4
        for (int tt = 0; tt < 64; tt++) {
            int t = (k << 6) + tt;
            float d0 = __shfl(dreg[k].x, tt, 64);
            float d1 = __shfl(dreg[k].y, tt, 64);
            float d2 = __shfl(dreg[k].z, tt, 64);
            outp[(size_t)t * (B_ * T_)]      = p0;   // pos_t before update
            outp[(size_t)t * (B_ * T_) + 64] = p1;
            float s0n = __shfl(p0, up, 64), s1n = __shfl(p1, up, 64);
            float s0p = __shfl(p0, dw, 64), s1p = __shfl(p1, dw, 64);
            float up0 = (lane == 63) ? s1n : s0n;   // pos[(l+1)%128], l=lane
            float dn0 = (lane == 0)  ? s1p : s0p;   // pos[(l-1)%128]
            float up1 = (lane == 63) ? s0n : s1n;   // l=lane+64
            float dn1 = (lane == 0)  ? s0p : s1p;
            p0 = fmaf(up0, d0, fmaf(p0, d1, dn0 * d2));
            p1 = fmaf(up1, d0, fmaf(p1, d1, dn1 * d2));
        }
    }
}

// ---------- Phase 2: the scan, 4-way tape-split.
// thread = (b, c, quarter q). Lanes: q = lane>>4, cl = lane&15.
// Each thread holds tape[l] for l in [32q, 32q+32) — 32 VGPRs, no AGPR spill.
// Dot-product over full tape = 2x shfl_xor (16, 32) across the 4 quarters.
// Grid: b = blk>>4, c covered 64 per block (4 waves x 16 lanes).
__global__ __launch_bounds__(256, 4) void k_scan(const float* __restrict__ values,
                                                 const float* __restrict__ dtr,
                                                 const float* __restrict__ pos_all,
                                                 float* __restrict__ tape_out) {
    int b    = blockIdx.x >> 4;
    int lane = threadIdx.x & 63;
    int wv   = threadIdx.x >> 6;          // wave in block, 0..3
    int q    = lane >> 4;                 // tape quarter, 0..3
    int cl   = lane & 15;
    int c    = ((blockIdx.x & 15) << 6) + (wv << 4) + cl;

    float tape[32];
#pragma unroll
    for (int l = 0; l < 32; l++) tape[l] = 0.f;

    const float* vp = values + (size_t)b * C_ + c;

    for (int t = 0; t < S_; t++) {
        float v  = vp[(size_t)t * (B_ * C_)];
        float rw = dtr[(((size_t)t << 6) + b) * 4 + 3];               // wave-uniform -> s_load
        const float4* p4 = (const float4*)(pos_all + ((size_t)t * B_ + b) * T_) + (q << 3);
        float4 p[8];
#pragma unroll
        for (int j = 0; j < 8; j++) p[j] = p4[j];
        float ov0 = 0.f, ov1 = 0.f, ov2 = 0.f, ov3 = 0.f;
#pragma unroll
        for (int j = 0; j < 8; j++) {
            ov0 = fmaf(tape[4 * j],     p[j].x, ov0);
            ov1 = fmaf(tape[4 * j + 1], p[j].y, ov1);
            ov2 = fmaf(tape[4 * j + 2], p[j].z, ov2);
            ov3 = fmaf(tape[4 * j + 3], p[j].w, ov3);
        }
        float ov = (ov0 + ov1) + (ov2 + ov3);
        ov += __shfl_xor(ov, 16, 64);
        ov += __shfl_xor(ov, 32, 64);
        float delta = (v - ov) * rw;
#pragma unroll
        for (int j = 0; j < 8; j++) {
            tape[4 * j]     = fmaf(p[j].x, delta, tape[4 * j]);
            tape[4 * j + 1] = fmaf(p[j].y, delta, tape[4 * j + 1]);
            tape[4 * j + 2] = fmaf(p[j].z, delta, tape[4 * j + 2]);
            tape[4 * j + 3] = fmaf(p[j].w, delta, tape[4 * j + 3]);
        }
    }
    // writeout: layout [l][b][c]; this thread owns l = 32q + j
    float* tp = tape_out + (size_t)b * C_ + c;
#pragma unroll
    for (int j = 0; j < 32; j++)
        tp[(size_t)(32 * q + j) * (B_ * C_)] = tape[j];
}

// ---------- Phase 3: LayerNorm over C + projection to V=10. one wave per (l,b).
__global__ __launch_bounds__(256) void k_out(const float* __restrict__ tape,
                                             const float* __restrict__ ln_g,
                                             const float* __restrict__ ln_b,
                                             const float* __restrict__ Wo,
                                             const float* __restrict__ bo,
                                             float* __restrict__ out) {
    int wid  = (blockIdx.x << 2) + (threadIdx.x >> 6);   // 0..8191 = l*64+b
    int lane = threadIdx.x & 63;
    const float* tr = tape + (size_t)wid * C_;
    float x[16];
    float s = 0.f, s2 = 0.f;
#pragma unroll
    for (int k = 0; k < 16; k++) {
        x[k] = tr[(k << 6) + lane];
        s += x[k];
        s2 = fmaf(x[k], x[k], s2);
    }
#pragma unroll
    for (int m = 1; m < 64; m <<= 1) {
        s  += __shfl_xor(s,  m, 64);
        s2 += __shfl_xor(s2, m, 64);
    }
    float mu = s * (1.f / C_);
    float var = s2 * (1.f / C_) - mu * mu;
    float rstd = rsqrtf(var + LN_EPS);
    float acc[V_];
#pragma unroll
    for (int v = 0; v < V_; v++) acc[v] = 0.f;
#pragma unroll
    for (int k = 0; k < 16; k++) {
        int cc = (k << 6) + lane;
        float h = fmaf((x[k] - mu) * rstd, ln_g[cc], ln_b[cc]);
#pragma unroll
        for (int v = 0; v < V_; v++) acc[v] = fmaf(h, Wo[v * C_ + cc], acc[v]);
    }
#pragma unroll
    for (int v = 0; v < V_; v++) {
#pragma unroll
        for (int m = 1; m < 64; m <<= 1) acc[v] += __shfl_xor(acc[v], m, 64);
    }
    if (lane == 0) {
#pragma unroll
        for (int v = 0; v < V_; v++) out[(size_t)wid * V_ + v] = acc[v] + bo[v];
    }
}

extern "C" void kernel_launch(void* const* d_in, const int* in_sizes, int n_in,
                              void* d_out, int out_size, void* d_ws, size_t ws_size,
                              hipStream_t stream) {
    const float* values = (const float*)d_in[0];
    const float* Wd     = (const float*)d_in[1];
    const float* bd     = (const float*)d_in[2];
    const float* Wr     = (const float*)d_in[3];
    const float* br     = (const float*)d_in[4];
    const float* ln_g   = (const float*)d_in[5];
    const float* ln_b   = (const float*)d_in[6];
    const float* Wo     = (const float*)d_in[7];
    const float* bo     = (const float*)d_in[8];
    float* out = (float*)d_out;

    // workspace layout (floats): dtr [512*64*4] | pos_all [512*64*128] | tape [128*64*1024]
    float* dtr     = (float*)d_ws;
    float* pos_all = dtr + (size_t)S_ * B_ * 4;
    float* tape    = pos_all + (size_t)S_ * B_ * T_;

    k_dirs<<<dim3((S_ * B_) / 4), dim3(256), 0, stream>>>(values, Wd, bd, Wr, br, dtr);
    k_pos <<<dim3(B_),            dim3(64),  0, stream>>>(dtr, pos_all);
    k_scan<<<dim3(B_ * 16),       dim3(256), 0, stream>>>(values, dtr, pos_all, tape);
    k_out <<<dim3((T_ * B_) / 4), dim3(256), 0, stream>>>(tape, ln_g, ln_b, Wo, bo, out);
}